// Round 8
// baseline (11692.648 us; speedup 1.0000x reference)
//
#include <hip/hip_runtime.h>

#define ALPHA 0.9f
#define THRESH 1.0f
#define BATCH 512
#define CIN 16
#define TSTEPS 2000
#define NRES 1024
#define NCLS 10

#define NPAIR 16        // 16 pairs; each pair = 2 groups x 16 batch rows
#define SLOTS 16        // blocks per pair; 64 neurons per slot

typedef int   v4i __attribute__((ext_vector_type(4)));
typedef float v4f __attribute__((ext_vector_type(4)));
typedef short v8s __attribute__((ext_vector_type(8)));

// ---- ws layout (bytes) ----
#define FLAGS_OFF  0        // 16 pairs x 2 parities x 16 dwords = 2 KB
#define SLOTC_OFF  8192     // max|W_clf| bits
#define ROWMAX_OFF 9216     // per-row max|W_res[n][:]|, 1024 floats
#define MASK_OFF   16384    // spike masks: 2 x 32 x 16 x 128 B = 128 KB
#define WQF_OFF    147456   // W_res int8, MFMA-fragment order: 1 MB
#define WCF_OFF    1196032  // W_clf int8 fragment tile: 16 KB

// ---- LDS layout (dynamic) ----
#define L_B   0                   // 64 KB weight slice (64 neurons x 1024 k)
#define L_A   65536               // 2 groups x 16 rows x 1040 B spike image
#define L_XA  (65536 + 33280)     // 2 groups x 1024 B bf16 x-image (hi|lo)
#define L_WC  (L_XA + 2048)       // 16 KB W_clf fragment (slot 0 only)
#define L_RC  (L_WC + 16384)      // 8 KB classifier partials
#define LDS_BYTES (L_RC + 8192)   // 125440 <= 160 KiB

__global__ __launch_bounds__(256) void maxabs_kernel(const float* __restrict__ W,
                                                     int n, unsigned* __restrict__ slot) {
    unsigned m = 0u;
    for (int i = blockIdx.x * 256 + threadIdx.x; i < n; i += gridDim.x * 256)
        m = max(m, __float_as_uint(W[i]) & 0x7fffffffu);
#pragma unroll
    for (int off = 32; off >= 1; off >>= 1)
        m = max(m, (unsigned)__shfl_xor((int)m, off, 64));
    if ((threadIdx.x & 63) == 0) atomicMax(slot, m);
}

// per-row max|W_res[n][:]| — one wave per row, plain store (deterministic)
__global__ __launch_bounds__(256) void rowmax_kernel(const float* __restrict__ W,
                                                     float* __restrict__ rowmax) {
    const int row = blockIdx.x * 4 + ((int)threadIdx.x >> 6);
    const int lane = threadIdx.x & 63;
    float m = 0.f;
    for (int j = lane; j < NRES; j += 64) m = fmaxf(m, fabsf(W[row * NRES + j]));
#pragma unroll
    for (int off = 32; off >= 1; off >>= 1) m = fmaxf(m, __shfl_xor(m, off, 64));
    if (lane == 0) rowmax[row] = m;
}

// W_res -> signed-int8 (PER-ROW scale), 64-neuron-slice MFMA B-fragment order:
// dword o4: sl=o4>>14, nt=(o4>>12)&3, kt=(o4>>8)&15, L=(o4>>2)&63, i0=(o4&3)*4
// n = sl*64 + nt*16 + (L&15); k = kt*64 + (L>>4)*16 + i0..+3
__global__ __launch_bounds__(256) void quant_res(const float* __restrict__ W,
                                                 const float* __restrict__ rowmax,
                                                 unsigned* __restrict__ dst) {
    const int o4 = blockIdx.x * 256 + threadIdx.x;
    const int sl = o4 >> 14, nt = (o4 >> 12) & 3, kt = (o4 >> 8) & 15;
    const int L = (o4 >> 2) & 63, i0 = (o4 & 3) * 4;
    const int n = sl * 64 + nt * 16 + (L & 15);
    const int k = kt * 64 + (L >> 4) * 16 + i0;
    const float inv = 127.0f / rowmax[n];
    unsigned dw = 0;
#pragma unroll
    for (int j = 0; j < 4; ++j) {
        float qv = rintf(W[n * NRES + k + j] * inv);
        qv = fminf(fmaxf(qv, -127.f), 127.f);
        dw |= ((unsigned)((int)qv & 0xff)) << (8 * j);
    }
    dst[o4] = dw;
}

// W_clf -> int8 fragment tile (16 cols, cls>=10 zero): 4096 dwords
__global__ __launch_bounds__(256) void quant_clf(const float* __restrict__ W,
                                                 const unsigned* __restrict__ slot,
                                                 unsigned* __restrict__ dst) {
    const int o4 = blockIdx.x * 256 + threadIdx.x;
    const int kt = (o4 >> 8) & 15, L = (o4 >> 2) & 63, i0 = (o4 & 3) * 4;
    const int cls = L & 15;
    const int k = kt * 64 + (L >> 4) * 16 + i0;
    const float inv = 127.0f / __uint_as_float(*slot);
    unsigned dw = 0;
    if (cls < NCLS) {
#pragma unroll
        for (int j = 0; j < 4; ++j) {
            float qv = rintf(W[cls * NRES + k + j] * inv);
            qv = fminf(fmaxf(qv, -127.f), 127.f);
            dw |= ((unsigned)((int)qv & 0xff)) << (8 * j);
        }
    }
    dst[o4] = dw;
}

__device__ __forceinline__ unsigned short f2bf(float f) {
    unsigned u = __float_as_uint(f);
    return (unsigned short)((u + 0x7fffu + ((u >> 16) & 1u)) >> 16);
}

// ---------------------------------------------------------------------------
// 256 blocks x 512 threads (1/CU). Block = (pair pr, slot sl): 64 neurons of
// TWO groups (2 x 16 batch rows). Waves 0-3 serve group A, 4-7 group B
// (shared LDS weight slice) — while one group's barrier lags, the other's
// waves keep the pipes busy. Barrier = 16 relaxed flag stores + 16-lane poll
// (no fences, no atomic RMW). Numerics identical to R7 (absmax must be 32).
// ---------------------------------------------------------------------------
__global__ __launch_bounds__(512, 1) void reservoir_mfma(
    const float* __restrict__ x, const float* __restrict__ W_in,
    unsigned char* __restrict__ ws, float* __restrict__ out)
{
    const int q   = (int)blockIdx.x;
    const int pr  = (q & 7) * 2 + ((q >> 3) & 1);  // pair (16 blocks, one XCD)
    const int sl  = q >> 4;                        // slot 0..15
    const int tid = (int)threadIdx.x;
    const int L    = tid & 63;
    const int wv   = tid >> 6;     // 0..7
    const int col  = L & 15;       // MFMA n-col (neuron) / cls
    const int rowq = L >> 4;       // batch quad
    const int G    = wv >> 2;      // my wave's group half
    const int nt   = wv & 3;       // my n-tile within the 64-neuron slice
    const int g    = pr * 2 + G;   // global group id

    extern __shared__ char lds[];
    char* B_lds = lds + L_B;
    char* A_g   = lds + L_A + G * 16640;
    unsigned short* xA_g = (unsigned short*)(lds + L_XA + G * 1024);
    char* WcL   = lds + L_WC;
    char* redC  = lds + L_RC;

    unsigned* flags = (unsigned*)(ws + FLAGS_OFF) + pr * 32;  // [parity][16]
    const float* rowmax = (const float*)(ws + ROWMAX_OFF);
    const float cscale = __uint_as_float(*(const unsigned*)(ws + SLOTC_OFF)) * (1.0f / 127.0f);
    unsigned char* maskbuf = ws + MASK_OFF;
    const unsigned char* wqf = ws + WQF_OFF;

    const int nn = sl * 64 + nt * 16 + col;          // my output neuron
    const float dscale = rowmax[nn] * (1.0f / 127.0f);
    const bool clfBlk = (sl == 0);

    // ---- load weight slice (64 KB) + classifier tile (slot 0)
    {
        const v4i* src = (const v4i*)(wqf + (size_t)sl * 65536);
        v4i* dst = (v4i*)B_lds;
        for (int i = tid; i < 4096; i += 512) dst[i] = src[i];
    }
    if (clfBlk) {
        const v4i* src = (const v4i*)(ws + WCF_OFF);
        v4i* dst = (v4i*)WcL;
        for (int i = tid; i < 1024; i += 512) dst[i] = src[i];
    }

    // ---- W_in hi/lo bf16 B-fragments for my n-tile
    v8s binf_h, binf_l;
#pragma unroll
    for (int i = 0; i < 8; ++i) {
        const int c = (rowq * 8 + i) & 15;
        const float w = W_in[nn * CIN + c];
        const unsigned short h = f2bf(w);
        const float wl = w - __uint_as_float((unsigned)h << 16);
        binf_h[i] = (short)h;
        binf_l[i] = (short)f2bf(wl);
    }

    float v[4]  = {0.f, 0.f, 0.f, 0.f};
    int   accv[4] = {0, 0, 0, 0};
    float vc[4] = {0.f, 0.f, 0.f, 0.f};   // live on waves 0/4 of slot 0
    int   accc[4] = {0, 0, 0, 0};

    // x pointer: 512 threads = 2 groups x 16 batches x 16 channels
    const int xG = tid >> 8, xb = (tid >> 4) & 15, xc = tid & 15;
    const float* xptr = x + ((size_t)((pr * 2 + xG) * 16 + xb) * CIN + xc) * TSTEPS;

    __syncthreads();

    for (int t = 0; t < TSTEPS; ++t) {
        const float xval = xptr[t];   // issued before the spin

        if (t > 0) {
            const int p = (t - 1) & 1;
            if (wv == 0) {
                const unsigned want = (unsigned)t;
                unsigned* f = flags + p * 16;
                for (;;) {
                    const unsigned val = (L < 16)
                        ? __hip_atomic_load(f + L, __ATOMIC_RELAXED, __HIP_MEMORY_SCOPE_AGENT)
                        : want;
                    if (__all((int)(val >= want))) break;
                    __builtin_amdgcn_s_sleep(1);
                }
            }
            __syncthreads();   // S1: both groups' masks of t-1 visible

            // ---- A-build for BOTH groups: thread (b, seg) expands 32 bits -> 32 B
            {
                const int b = tid >> 5, seg = tid & 31;
                const unsigned* mpA = (const unsigned*)(maskbuf +
                    (size_t)((p * 32 + pr * 2 + 0) * 16 + b) * 128 + seg * 4);
                const unsigned* mpB = (const unsigned*)(maskbuf +
                    (size_t)((p * 32 + pr * 2 + 1) * 16 + b) * 128 + seg * 4);
                const unsigned mA = __hip_atomic_load(mpA, __ATOMIC_RELAXED, __HIP_MEMORY_SCOPE_AGENT);
                const unsigned mB = __hip_atomic_load(mpB, __ATOMIC_RELAXED, __HIP_MEMORY_SCOPE_AGENT);
                unsigned wA[8], wB[8];
#pragma unroll
                for (int d = 0; d < 8; ++d) {
                    const unsigned ma = mA >> (4 * d), mb = mB >> (4 * d);
                    wA[d] = (ma & 1u) | ((ma & 2u) << 7) | ((ma & 4u) << 14) | ((ma & 8u) << 21);
                    wB[d] = (mb & 1u) | ((mb & 2u) << 7) | ((mb & 4u) << 14) | ((mb & 8u) << 21);
                }
                v4i* dA = (v4i*)(lds + L_A + 0 * 16640 + b * 1040 + seg * 32);
                v4i* dB = (v4i*)(lds + L_A + 1 * 16640 + b * 1040 + seg * 32);
                dA[0] = *(v4i*)&wA[0]; dA[1] = *(v4i*)&wA[4];
                dB[0] = *(v4i*)&wB[0]; dB[1] = *(v4i*)&wB[4];
            }
        }
        // ---- stage x_t hi/lo into my group's x-image
        {
            unsigned short* xa = (unsigned short*)(lds + L_XA + xG * 1024);
            const unsigned short h = f2bf(xval);
            const float lo = xval - __uint_as_float((unsigned)h << 16);
            xa[xb * 32 + xc] = h;
            xa[xb * 32 + 16 + xc] = f2bf(lo);
        }
        __syncthreads();   // S2: A + xA ready

        // ---- input projection: (xh+xl).(Wh+Wl) via 2 chained bf16 MFMAs
        v4f Din;
        {
            const v8s xa = *(const v8s*)((const char*)xA_g + col * 64 + rowq * 16);
            v4f z = {0.f, 0.f, 0.f, 0.f};
            const v4f D1 = __builtin_amdgcn_mfma_f32_16x16x32_bf16(xa, binf_h, z, 0, 0, 0);
            Din = __builtin_amdgcn_mfma_f32_16x16x32_bf16(xa, binf_l, D1, 0, 0, 0);
        }

        // ---- recurrent: 16 x mfma_i32_16x16x64_i8 over my group's A image
        v4i Drec = {0, 0, 0, 0};
        if (t > 0) {
            const char* Bb = B_lds + nt * 16384;
            const char* Ab = A_g + col * 1040 + rowq * 16;
#pragma unroll 4
            for (int kt = 0; kt < 16; ++kt) {
                const v4i af = *(const v4i*)(Ab + kt * 64);
                const v4i bf = *(const v4i*)(Bb + kt * 1024 + L * 16);
                Drec = __builtin_amdgcn_mfma_i32_16x16x64_i8(af, bf, Drec, 0, 0, 0);
            }
        }

        // ---- classifier partials (slot 0): wave handles 4 kt of its group
        if (clfBlk && t > 0) {
            v4i Dc = {0, 0, 0, 0};
            const char* Ab = A_g + col * 1040 + rowq * 16;
#pragma unroll
            for (int kk = 0; kk < 4; ++kk) {
                const int kt = nt * 4 + kk;
                const v4i af = *(const v4i*)(Ab + kt * 64);
                const v4i bf = *(const v4i*)(WcL + kt * 1024 + L * 16);
                Dc = __builtin_amdgcn_mfma_i32_16x16x64_i8(af, bf, Dc, 0, 0, 0);
            }
            *(v4i*)(redC + wv * 1024 + L * 16) = Dc;
        }
        __syncthreads();   // S3: classifier partials ready; A image consumed

        // ---- LIF + spikes + ballots (all 8 waves, each its (G, nt) tile)
        unsigned long long bal0, bal1, bal2, bal3;
        {
            float vn; int s;
            vn = ALPHA * v[0] + Din[0] + dscale * (float)Drec[0];
            s = (vn >= THRESH); accv[0] += s; v[0] = s ? 0.f : vn; bal0 = __ballot(s);
            vn = ALPHA * v[1] + Din[1] + dscale * (float)Drec[1];
            s = (vn >= THRESH); accv[1] += s; v[1] = s ? 0.f : vn; bal1 = __ballot(s);
            vn = ALPHA * v[2] + Din[2] + dscale * (float)Drec[2];
            s = (vn >= THRESH); accv[2] += s; v[2] = s ? 0.f : vn; bal2 = __ballot(s);
            vn = ALPHA * v[3] + Din[3] + dscale * (float)Drec[3];
            s = (vn >= THRESH); accv[3] += s; v[3] = s ? 0.f : vn; bal3 = __ballot(s);
        }

        // ---- publish: lanes 0..15 store batch L's 16-bit field (agent relaxed)
        {
            const int p = t & 1;
            if (L < 16) {
                const int b = L;
                const unsigned long long bb = (b & 2) ? ((b & 1) ? bal3 : bal2)
                                                      : ((b & 1) ? bal1 : bal0);
                const unsigned short fld = (unsigned short)((bb >> ((b >> 2) * 16)) & 0xFFFFu);
                unsigned short* mp = (unsigned short*)(maskbuf +
                    (size_t)((p * 32 + g) * 16 + b) * 128 + sl * 8 + nt * 2);
                __hip_atomic_store(mp, fld, __ATOMIC_RELAXED, __HIP_MEMORY_SCOPE_AGENT);
            }
        }

        // ---- classifier reduce + LIF (slot 0, waves 0 and 4)
        if (clfBlk && nt == 0 && t > 0) {
            const v4i c0 = *(const v4i*)(redC + (G * 4 + 0) * 1024 + L * 16);
            const v4i c1 = *(const v4i*)(redC + (G * 4 + 1) * 1024 + L * 16);
            const v4i c2 = *(const v4i*)(redC + (G * 4 + 2) * 1024 + L * 16);
            const v4i c3 = *(const v4i*)(redC + (G * 4 + 3) * 1024 + L * 16);
#pragma unroll
            for (int r = 0; r < 4; ++r) {
                const int dc = (c0[r] + c1[r]) + (c2[r] + c3[r]);
                const float vcn = ALPHA * vc[r] + cscale * (float)dc;
                const int sc = (vcn >= THRESH);
                accc[r] += sc;
                vc[r] = sc ? 0.f : vcn;
            }
        }
        __syncthreads();   // S4: drains every wave's mask stores (vmcnt before s_barrier)

        if (tid == 0) {
            asm volatile("s_waitcnt vmcnt(0) lgkmcnt(0)" ::: "memory");
            __hip_atomic_store(flags + (t & 1) * 16 + sl, (unsigned)(t + 1),
                               __ATOMIC_RELAXED, __HIP_MEMORY_SCOPE_AGENT);
        }
    }

    // ---- epilogue: classifier flush with s_{T-1} (parity 1) + outputs
    if (clfBlk) {
        if (wv == 0) {
            unsigned* f = flags + 1 * 16;
            for (;;) {
                const unsigned val = (L < 16)
                    ? __hip_atomic_load(f + L, __ATOMIC_RELAXED, __HIP_MEMORY_SCOPE_AGENT)
                    : (unsigned)TSTEPS;
                if (__all((int)(val >= (unsigned)TSTEPS))) break;
                __builtin_amdgcn_s_sleep(1);
            }
        }
        __syncthreads();
        {
            const int b = tid >> 5, seg = tid & 31;
#pragma unroll
            for (int Gi = 0; Gi < 2; ++Gi) {
                const unsigned* mp = (const unsigned*)(maskbuf +
                    (size_t)((1 * 32 + pr * 2 + Gi) * 16 + b) * 128 + seg * 4);
                const unsigned m = __hip_atomic_load(mp, __ATOMIC_RELAXED, __HIP_MEMORY_SCOPE_AGENT);
                unsigned w[8];
#pragma unroll
                for (int d = 0; d < 8; ++d) {
                    const unsigned mm = m >> (4 * d);
                    w[d] = (mm & 1u) | ((mm & 2u) << 7) | ((mm & 4u) << 14) | ((mm & 8u) << 21);
                }
                v4i* dst = (v4i*)(lds + L_A + Gi * 16640 + b * 1040 + seg * 32);
                dst[0] = *(v4i*)&w[0]; dst[1] = *(v4i*)&w[4];
            }
        }
        __syncthreads();
        {
            v4i Dc = {0, 0, 0, 0};
            const char* Ab = A_g + col * 1040 + rowq * 16;
#pragma unroll
            for (int kk = 0; kk < 4; ++kk) {
                const int kt = nt * 4 + kk;
                const v4i af = *(const v4i*)(Ab + kt * 64);
                const v4i bf = *(const v4i*)(WcL + kt * 1024 + L * 16);
                Dc = __builtin_amdgcn_mfma_i32_16x16x64_i8(af, bf, Dc, 0, 0, 0);
            }
            *(v4i*)(redC + wv * 1024 + L * 16) = Dc;
        }
        __syncthreads();
        if (nt == 0 && col < NCLS) {
            const v4i c0 = *(const v4i*)(redC + (G * 4 + 0) * 1024 + L * 16);
            const v4i c1 = *(const v4i*)(redC + (G * 4 + 1) * 1024 + L * 16);
            const v4i c2 = *(const v4i*)(redC + (G * 4 + 2) * 1024 + L * 16);
            const v4i c3 = *(const v4i*)(redC + (G * 4 + 3) * 1024 + L * 16);
#pragma unroll
            for (int r = 0; r < 4; ++r) {
                const int dc = (c0[r] + c1[r]) + (c2[r] + c3[r]);
                const float vcn = ALPHA * vc[r] + cscale * (float)dc;
                const int sc = (vcn >= THRESH);
                out[(size_t)(g * 16 + rowq * 4 + r) * NCLS + col] = (float)(accc[r] + sc);
            }
        }
    }
    {
#pragma unroll
        for (int r = 0; r < 4; ++r) {
            const int bglob = g * 16 + rowq * 4 + r;
            out[BATCH * NCLS + (size_t)bglob * NRES + nn] = (float)accv[r];
        }
    }
}

extern "C" void kernel_launch(void* const* d_in, const int* in_sizes, int n_in,
                              void* d_out, int out_size, void* d_ws, size_t ws_size,
                              hipStream_t stream) {
    (void)in_sizes; (void)n_in; (void)out_size; (void)ws_size;
    const float* x     = (const float*)d_in[0];
    const float* W_in  = (const float*)d_in[1];
    const float* W_res = (const float*)d_in[2];
    const float* W_clf = (const float*)d_in[3];
    float* out = (float*)d_out;
    unsigned char* ws = (unsigned char*)d_ws;

    hipMemsetAsync(ws, 0, 16384, stream);  // flags + clf slot + rowmax region
    rowmax_kernel<<<256, 256, 0, stream>>>(W_res, (float*)(ws + ROWMAX_OFF));
    maxabs_kernel<<<16, 256, 0, stream>>>(W_clf, NCLS * NRES, (unsigned*)(ws + SLOTC_OFF));
    quant_res<<<1024, 256, 0, stream>>>(W_res, (const float*)(ws + ROWMAX_OFF),
                                        (unsigned*)(ws + WQF_OFF));
    quant_clf<<<16, 256, 0, stream>>>(W_clf, (const unsigned*)(ws + SLOTC_OFF),
                                      (unsigned*)(ws + WCF_OFF));
    reservoir_mfma<<<NPAIR * SLOTS, 512, LDS_BYTES, stream>>>(x, W_in, ws, out);
}

// Round 9
// 5159.921 us; speedup vs baseline: 2.2661x; 2.2661x over previous
//
#include <hip/hip_runtime.h>

#define ALPHA 0.9f
#define THRESH 1.0f
#define BATCH 512
#define CIN 16
#define TSTEPS 2000
#define NRES 1024
#define NCLS 10

#define NGROUP 32       // 32 batch groups of 16 rows
#define BPG 8           // blocks per group, 128 neurons each

typedef int   v4i __attribute__((ext_vector_type(4)));
typedef float v4f __attribute__((ext_vector_type(4)));
typedef short v8s __attribute__((ext_vector_type(8)));

// ---- ws layout (bytes) ----
#define SLOTC_OFF  8192     // max|W_clf| bits
#define ROWMAX_OFF 9216     // per-row max|W_res[n][:]|, 1024 floats
#define MASK_OFF   16384    // tagged masks: 2 par x 32 g x 16 b x 64 prod x 4 B = 256 KB
#define WQF_OFF    278528   // W_res int8, MFMA-fragment order: 1 MB
#define WCF_OFF    1327104  // W_clf int8 fragment tile: 16 KB
#define LDS_BYTES  (131072 + 16*1040 + 1024 + 8192)  // B slice + A + xA + redC

__global__ __launch_bounds__(256) void maxabs_kernel(const float* __restrict__ W,
                                                     int n, unsigned* __restrict__ slot) {
    unsigned m = 0u;
    for (int i = blockIdx.x * 256 + threadIdx.x; i < n; i += gridDim.x * 256)
        m = max(m, __float_as_uint(W[i]) & 0x7fffffffu);
#pragma unroll
    for (int off = 32; off >= 1; off >>= 1)
        m = max(m, (unsigned)__shfl_xor((int)m, off, 64));
    if ((threadIdx.x & 63) == 0) atomicMax(slot, m);
}

// per-row max|W_res[n][:]| — one wave per row, plain store (deterministic)
__global__ __launch_bounds__(256) void rowmax_kernel(const float* __restrict__ W,
                                                     float* __restrict__ rowmax) {
    const int row = blockIdx.x * 4 + ((int)threadIdx.x >> 6);
    const int lane = threadIdx.x & 63;
    float m = 0.f;
    for (int j = lane; j < NRES; j += 64) m = fmaxf(m, fabsf(W[row * NRES + j]));
#pragma unroll
    for (int off = 32; off >= 1; off >>= 1) m = fmaxf(m, __shfl_xor(m, off, 64));
    if (lane == 0) rowmax[row] = m;
}

// W_res -> signed-int8 (PER-ROW scale) in MFMA B-fragment order:
// dword o4: bl=o4>>15, wv=(o4>>12)&7, kt=(o4>>8)&15, L=(o4>>2)&63, i0=(o4&3)*4
// n = bl*128+wv*16+(L&15); k = kt*64+(L>>4)*16+i0..+3
__global__ __launch_bounds__(256) void quant_res(const float* __restrict__ W,
                                                 const float* __restrict__ rowmax,
                                                 unsigned* __restrict__ dst) {
    const int o4 = blockIdx.x * 256 + threadIdx.x;
    const int bl = o4 >> 15, wv = (o4 >> 12) & 7, kt = (o4 >> 8) & 15;
    const int L = (o4 >> 2) & 63, i0 = (o4 & 3) * 4;
    const int n = bl * 128 + wv * 16 + (L & 15);
    const int k = kt * 64 + (L >> 4) * 16 + i0;
    const float inv = 127.0f / rowmax[n];
    unsigned dw = 0;
#pragma unroll
    for (int j = 0; j < 4; ++j) {
        float q = rintf(W[n * NRES + k + j] * inv);
        q = fminf(fmaxf(q, -127.f), 127.f);
        dw |= ((unsigned)((int)q & 0xff)) << (8 * j);
    }
    dst[o4] = dw;
}

// W_clf -> int8 fragment tile (16 cols, cls>=10 zero): 4096 dwords
__global__ __launch_bounds__(256) void quant_clf(const float* __restrict__ W,
                                                 const unsigned* __restrict__ slot,
                                                 unsigned* __restrict__ dst) {
    const int o4 = blockIdx.x * 256 + threadIdx.x;
    const int kt = (o4 >> 8) & 15, L = (o4 >> 2) & 63, i0 = (o4 & 3) * 4;
    const int cls = L & 15;
    const int k = kt * 64 + (L >> 4) * 16 + i0;
    const float inv = 127.0f / __uint_as_float(*slot);
    unsigned dw = 0;
    if (cls < NCLS) {
#pragma unroll
        for (int j = 0; j < 4; ++j) {
            float q = rintf(W[cls * NRES + k + j] * inv);
            q = fminf(fmaxf(q, -127.f), 127.f);
            dw |= ((unsigned)((int)q & 0xff)) << (8 * j);
        }
    }
    dst[o4] = dw;
}

__device__ __forceinline__ unsigned short f2bf(float f) {
    unsigned u = __float_as_uint(f);
    return (unsigned short)((u + 0x7fffu + ((u >> 16) & 1u)) >> 16);
}

// ---------------------------------------------------------------------------
// 256 blocks x 512 threads (1/CU). Block = (group g, slot bl): 16 batch rows
// x 128 neurons, int8 W slice LDS-resident. Inter-block sync = SELF-VALIDATING
// TAGGED MASKS: producer wave stores dword (tag<<16|field); all 512 consumer
// threads poll their 8-B mask pair until tags==t (data IS the flag — no
// drains, no flag RMW convoy, one coherence-point round-trip per step).
// Numerics identical to R7 (absmax must be exactly 32).
// ---------------------------------------------------------------------------
__global__ __launch_bounds__(512, 1) void reservoir_mfma(
    const float* __restrict__ x, const float* __restrict__ W_in,
    unsigned char* __restrict__ ws, float* __restrict__ out)
{
    // XCD co-location: 8 blocks of a group share q%8 (dispatch heuristic).
    const int q   = (int)blockIdx.x;
    const int g   = (q & 7) * 4 + ((q >> 3) & 3);
    const int bl  = q >> 5;
    const int tid = (int)threadIdx.x;
    const int L    = tid & 63;
    const int wv   = tid >> 6;     // 0..7
    const int col  = L & 15;       // MFMA n-col (neuron/cls)
    const int rowq = L >> 4;       // batch quad

    extern __shared__ char lds[];
    char* B_lds = lds;                                   // 131072 B
    char* A_lds = lds + 131072;                          // 16 x 1040 B
    unsigned short* xA = (unsigned short*)(lds + 131072 + 16 * 1040);  // 16x32 bf16
    char* redC = lds + 131072 + 16 * 1040 + 1024;        // 8 KB clf partials

    const float* rowmax = (const float*)(ws + ROWMAX_OFF);
    const float cscale = __uint_as_float(*(const unsigned*)(ws + SLOTC_OFF)) * (1.0f / 127.0f);
    unsigned char* maskbuf = ws + MASK_OFF;
    const unsigned char* wqf = ws + WQF_OFF;
    const unsigned char* wcf = ws + WCF_OFF;

    const int nn = bl * 128 + wv * 16 + col;             // my output neuron
    const float dscale = rowmax[nn] * (1.0f / 127.0f);
    const bool clfBlk = (bl == 0);

    // ---- load my 128 KB weight slice into LDS
    {
        const v4i* src = (const v4i*)(wqf + (size_t)bl * 131072);
        v4i* dst = (v4i*)B_lds;
        for (int i = tid; i < 8192; i += 512) dst[i] = src[i];
    }

    // ---- W_in hi/lo bf16 B-fragments
    v8s binf_h, binf_l;
#pragma unroll
    for (int i = 0; i < 8; ++i) {
        const int c = (rowq * 8 + i) & 15;
        const float w = W_in[nn * CIN + c];
        const unsigned short h = f2bf(w);
        const float wl = w - __uint_as_float((unsigned)h << 16);
        binf_h[i] = (short)h;
        binf_l[i] = (short)f2bf(wl);
    }

    // ---- classifier fragments preloaded to registers (block 0: wave wv owns kt=2wv,2wv+1)
    v4i bcf0 = {0,0,0,0}, bcf1 = {0,0,0,0};
    if (clfBlk) {
        bcf0 = *(const v4i*)(wcf + (2 * wv + 0) * 1024 + L * 16);
        bcf1 = *(const v4i*)(wcf + (2 * wv + 1) * 1024 + L * 16);
    }

    float v[4]  = {0.f, 0.f, 0.f, 0.f};
    int   accv[4] = {0, 0, 0, 0};
    float vc[4] = {0.f, 0.f, 0.f, 0.f};   // live on block0/wave0
    int   accc[4] = {0, 0, 0, 0};

    const int mb = tid >> 5, mseg = tid & 31;   // my mask-poll / A-build slot
    const unsigned long long* mybase0 = (const unsigned long long*)(maskbuf +
        (size_t)((0 * NGROUP + g) * 16 + mb) * 256 + mseg * 8);
    const unsigned long long* mybase1 = (const unsigned long long*)(maskbuf +
        (size_t)((1 * NGROUP + g) * 16 + mb) * 256 + mseg * 8);

    __syncthreads();

    for (int t = 0; t < TSTEPS; ++t) {
        // x_t load issued before the poll
        float xval = 0.f;
        if (tid < 256) {
            const int b = tid >> 4, c = tid & 15;
            xval = x[((size_t)(g * 16 + b) * CIN + c) * TSTEPS + t];
        }

        if (t > 0) {
            // ---- poll tagged masks of step t-1 (parity (t-1)&1), expand to A
            const unsigned long long* mp = ((t - 1) & 1) ? mybase1 : mybase0;
            const unsigned want = (unsigned)t;
            unsigned lo, hi;
            for (;;) {
                const unsigned long long u =
                    __hip_atomic_load(mp, __ATOMIC_RELAXED, __HIP_MEMORY_SCOPE_AGENT);
                lo = (unsigned)u; hi = (unsigned)(u >> 32);
                if (((lo >> 16) == want) & ((hi >> 16) == want)) break;
                __builtin_amdgcn_s_sleep(1);
            }
            const unsigned m = (lo & 0xffffu) | ((hi & 0xffffu) << 16);
            unsigned w[8];
#pragma unroll
            for (int d = 0; d < 8; ++d) {
                const unsigned mm = m >> (4 * d);
                w[d] = (mm & 1u) | ((mm & 2u) << 7) | ((mm & 4u) << 14) | ((mm & 8u) << 21);
            }
            v4i* dst = (v4i*)(A_lds + mb * 1040 + mseg * 32);
            dst[0] = *(v4i*)&w[0];
            dst[1] = *(v4i*)&w[4];
        }
        // ---- stage x_t hi/lo
        if (tid < 256) {
            const int b = tid >> 4, c = tid & 15;
            const unsigned short h = f2bf(xval);
            const float lo2 = xval - __uint_as_float((unsigned)h << 16);
            xA[b * 32 + c] = h;
            xA[b * 32 + 16 + c] = f2bf(lo2);
        }
        __syncthreads();   // S2: A + xA ready

        // ---- input projection: (xh+xl).(Wh+Wl), 2 chained bf16 MFMAs
        v4f Din;
        {
            const v8s xa = *(const v8s*)((const char*)xA + col * 64 + rowq * 16);
            v4f z = {0.f, 0.f, 0.f, 0.f};
            const v4f D1 = __builtin_amdgcn_mfma_f32_16x16x32_bf16(xa, binf_h, z, 0, 0, 0);
            Din = __builtin_amdgcn_mfma_f32_16x16x32_bf16(xa, binf_l, D1, 0, 0, 0);
        }

        // ---- recurrent: 16 x mfma_i32_16x16x64_i8, 2 independent chains (exact)
        v4i Drec = {0, 0, 0, 0};
        if (t > 0) {
            const char* Bb = B_lds + wv * 16384;
            const char* Ab = A_lds + col * 1040 + rowq * 16;
            v4i Dr0 = {0,0,0,0}, Dr1 = {0,0,0,0};
#pragma unroll 4
            for (int kt = 0; kt < 16; kt += 2) {
                const v4i a0 = *(const v4i*)(Ab + kt * 64);
                const v4i b0 = *(const v4i*)(Bb + kt * 1024 + L * 16);
                const v4i a1 = *(const v4i*)(Ab + (kt + 1) * 64);
                const v4i b1 = *(const v4i*)(Bb + (kt + 1) * 1024 + L * 16);
                Dr0 = __builtin_amdgcn_mfma_i32_16x16x64_i8(a0, b0, Dr0, 0, 0, 0);
                Dr1 = __builtin_amdgcn_mfma_i32_16x16x64_i8(a1, b1, Dr1, 0, 0, 0);
            }
#pragma unroll
            for (int r = 0; r < 4; ++r) Drec[r] = Dr0[r] + Dr1[r];
        }

        // ---- classifier partials (block 0, spread: wave wv does kt=2wv,2wv+1)
        if (clfBlk && t > 0) {
            const char* Ab = A_lds + col * 1040 + rowq * 16;
            v4i Dc = {0, 0, 0, 0};
            const v4i a0 = *(const v4i*)(Ab + (2 * wv + 0) * 64);
            const v4i a1 = *(const v4i*)(Ab + (2 * wv + 1) * 64);
            Dc = __builtin_amdgcn_mfma_i32_16x16x64_i8(a0, bcf0, Dc, 0, 0, 0);
            Dc = __builtin_amdgcn_mfma_i32_16x16x64_i8(a1, bcf1, Dc, 0, 0, 0);
            *(v4i*)(redC + wv * 1024 + L * 16) = Dc;
        }
        __syncthreads();   // S3: A consumed; redC ready

        // ---- LIF + spikes + ballots
        unsigned long long bal0, bal1, bal2, bal3;
        {
            float vn; int s;
            vn = ALPHA * v[0] + Din[0] + dscale * (float)Drec[0];
            s = (vn >= THRESH); accv[0] += s; v[0] = s ? 0.f : vn; bal0 = __ballot(s);
            vn = ALPHA * v[1] + Din[1] + dscale * (float)Drec[1];
            s = (vn >= THRESH); accv[1] += s; v[1] = s ? 0.f : vn; bal1 = __ballot(s);
            vn = ALPHA * v[2] + Din[2] + dscale * (float)Drec[2];
            s = (vn >= THRESH); accv[2] += s; v[2] = s ? 0.f : vn; bal2 = __ballot(s);
            vn = ALPHA * v[3] + Din[3] + dscale * (float)Drec[3];
            s = (vn >= THRESH); accv[3] += s; v[3] = s ? 0.f : vn; bal3 = __ballot(s);
        }

        // ---- publish tagged mask dword (tag = t+1), lanes 0..15
        {
            const int p = t & 1;
            if (L < 16) {
                const int b = L;
                const unsigned long long bb = (b & 2) ? ((b & 1) ? bal3 : bal2)
                                                      : ((b & 1) ? bal1 : bal0);
                const unsigned fld = (unsigned)((bb >> ((b >> 2) * 16)) & 0xFFFFu);
                unsigned* mp = (unsigned*)(maskbuf +
                    (size_t)((p * NGROUP + g) * 16 + b) * 256 + (bl * 8 + wv) * 4);
                __hip_atomic_store(mp, ((unsigned)(t + 1) << 16) | fld,
                                   __ATOMIC_RELAXED, __HIP_MEMORY_SCOPE_AGENT);
            }
        }

        // ---- classifier reduce + LIF (block 0, wave 0; reads redC after S3)
        if (clfBlk && wv == 0 && t > 0) {
            v4i c0 = *(const v4i*)(redC + 0 * 1024 + L * 16);
#pragma unroll
            for (int j = 1; j < 8; ++j) {
                const v4i cj = *(const v4i*)(redC + j * 1024 + L * 16);
#pragma unroll
                for (int r = 0; r < 4; ++r) c0[r] += cj[r];
            }
#pragma unroll
            for (int r = 0; r < 4; ++r) {
                const float vcn = ALPHA * vc[r] + cscale * (float)c0[r];
                const int sc = (vcn >= THRESH);
                accc[r] += sc;
                vc[r] = sc ? 0.f : vcn;
            }
        }
        // no end-of-loop barrier: each thread's next-step poll gates its own
        // A-build write; S2/S3 order all LDS hazards (see analysis).
    }

    // ---- epilogue: classifier flush with s_{T-1} (parity 1, tag TSTEPS)
    if (clfBlk) {
        {
            const unsigned want = (unsigned)TSTEPS;
            unsigned lo, hi;
            for (;;) {
                const unsigned long long u =
                    __hip_atomic_load(mybase1, __ATOMIC_RELAXED, __HIP_MEMORY_SCOPE_AGENT);
                lo = (unsigned)u; hi = (unsigned)(u >> 32);
                if (((lo >> 16) == want) & ((hi >> 16) == want)) break;
                __builtin_amdgcn_s_sleep(1);
            }
            const unsigned m = (lo & 0xffffu) | ((hi & 0xffffu) << 16);
            unsigned w[8];
#pragma unroll
            for (int d = 0; d < 8; ++d) {
                const unsigned mm = m >> (4 * d);
                w[d] = (mm & 1u) | ((mm & 2u) << 7) | ((mm & 4u) << 14) | ((mm & 8u) << 21);
            }
            v4i* dst = (v4i*)(A_lds + mb * 1040 + mseg * 32);
            dst[0] = *(v4i*)&w[0];
            dst[1] = *(v4i*)&w[4];
        }
        __syncthreads();
        {
            const char* Ab = A_lds + col * 1040 + rowq * 16;
            v4i Dc = {0, 0, 0, 0};
            const v4i a0 = *(const v4i*)(Ab + (2 * wv + 0) * 64);
            const v4i a1 = *(const v4i*)(Ab + (2 * wv + 1) * 64);
            Dc = __builtin_amdgcn_mfma_i32_16x16x64_i8(a0, bcf0, Dc, 0, 0, 0);
            Dc = __builtin_amdgcn_mfma_i32_16x16x64_i8(a1, bcf1, Dc, 0, 0, 0);
            *(v4i*)(redC + wv * 1024 + L * 16) = Dc;
        }
        __syncthreads();
        if (wv == 0 && col < NCLS) {
            v4i c0 = *(const v4i*)(redC + 0 * 1024 + L * 16);
#pragma unroll
            for (int j = 1; j < 8; ++j) {
                const v4i cj = *(const v4i*)(redC + j * 1024 + L * 16);
#pragma unroll
                for (int r = 0; r < 4; ++r) c0[r] += cj[r];
            }
#pragma unroll
            for (int r = 0; r < 4; ++r) {
                const float vcn = ALPHA * vc[r] + cscale * (float)c0[r];
                const int sc = (vcn >= THRESH);
                out[(size_t)(g * 16 + rowq * 4 + r) * NCLS + col] = (float)(accc[r] + sc);
            }
        }
    }
    {
#pragma unroll
        for (int r = 0; r < 4; ++r) {
            const int bglob = g * 16 + rowq * 4 + r;
            out[BATCH * NCLS + (size_t)bglob * NRES + nn] = (float)accv[r];
        }
    }
}

extern "C" void kernel_launch(void* const* d_in, const int* in_sizes, int n_in,
                              void* d_out, int out_size, void* d_ws, size_t ws_size,
                              hipStream_t stream) {
    (void)in_sizes; (void)n_in; (void)out_size; (void)ws_size;
    const float* x     = (const float*)d_in[0];
    const float* W_in  = (const float*)d_in[1];
    const float* W_res = (const float*)d_in[2];
    const float* W_clf = (const float*)d_in[3];
    float* out = (float*)d_out;
    unsigned char* ws = (unsigned char*)d_ws;

    // zero: scale slots + rowmax + ENTIRE tagged-mask region (tags 0 never match)
    hipMemsetAsync(ws, 0, MASK_OFF + 262144, stream);
    rowmax_kernel<<<256, 256, 0, stream>>>(W_res, (float*)(ws + ROWMAX_OFF));
    maxabs_kernel<<<16, 256, 0, stream>>>(W_clf, NCLS * NRES, (unsigned*)(ws + SLOTC_OFF));
    quant_res<<<1024, 256, 0, stream>>>(W_res, (const float*)(ws + ROWMAX_OFF),
                                        (unsigned*)(ws + WQF_OFF));
    quant_clf<<<16, 256, 0, stream>>>(W_clf, (const unsigned*)(ws + SLOTC_OFF),
                                      (unsigned*)(ws + WCF_OFF));
    reservoir_mfma<<<NGROUP * BPG, 512, LDS_BYTES, stream>>>(x, W_in, ws, out);
}